// Round 1
// baseline (267.906 us; speedup 1.0000x reference)
//
#include <hip/hip_runtime.h>

// CTC forward loss (log-space alpha recursion), MI355X.
// predictions (B,T,C) f32 log-probs, targets (B,L) i32, pred_lengths (B) i32,
// target_lengths (B) i32 -> scalar mean loss (f32).
//
// Design: one block of 256 threads per batch element. Thread s owns lattice
// state s (thread 0 also owns state 256). Alpha double-buffered in LDS,
// 1 barrier/step. Base-2 log space (v_exp_f32/v_log_f32 native). Emission
// column per state is time-invariant -> 8-deep register prefetch ring.

static constexpr float LOG2E_F = 1.4426950408889634f;
static constexpr float LN2_F   = 0.6931471805599453f;
#define NEGF (-1.0e30f)

#if __has_builtin(__builtin_amdgcn_exp2f)
#define FEXP2(x) __builtin_amdgcn_exp2f(x)
#else
#define FEXP2(x) exp2f(x)
#endif
#if __has_builtin(__builtin_amdgcn_logf)
#define FLOG2(x) __builtin_amdgcn_logf(x)
#else
#define FLOG2(x) __log2f(x)
#endif

template <int T, int C, int L>
__global__ __launch_bounds__(256) void ctc_alpha_kernel(
    const float* __restrict__ pred,      // (B,T,C)
    const int*   __restrict__ targets,   // (B,L)
    const int*   __restrict__ pred_len,  // (B)
    const int*   __restrict__ tgt_len,   // (B)
    float*       __restrict__ per_ex)    // (B) loss/target_len per example
{
  constexpr int S = 2 * L + 1;  // 257
  const int b = blockIdx.x;
  const int s = threadIdx.x;    // state id 0..255; thread 0 also owns state 256

  // alpha[state] stored at index state+2; [0],[1] are permanent NEG pads so
  // the generic lse3 formula is correct for s=0,1 without branches.
  __shared__ float abuf[2][S + 3];

  const float* __restrict__ prow = pred + (size_t)b * T * C;
  const int plen = pred_len[b];
  const int tl   = tgt_len[b];

  // Per-thread emission column and skip flag (time-invariant).
  int col;
  bool skip;
  if (s & 1) {
    const int ti = (s - 1) >> 1;
    col  = targets[b * L + ti];
    skip = (s == 1) ? true : (col != targets[b * L + ti - 1]);
  } else {
    col  = 0;  // blank
    skip = false;
  }

  // t = 0 init: alpha0[0] = emit(0, blank), alpha0[1] = emit(0, tgt0), else NEG.
  float a1;                 // own state's alpha (base-2 space)
  float a256 = NEGF;        // thread 0 only: state 256
  {
    const float e0 = prow[col] * LOG2E_F;
    a1 = (s <= 1) ? e0 : NEGF;
  }
  abuf[0][s + 2] = a1;
  if (s == 0) {
    abuf[0][0] = NEGF; abuf[0][1] = NEGF;
    abuf[1][0] = NEGF; abuf[1][1] = NEGF;
    abuf[0][S + 1] = a256;  // state 256 slot
  }
  __syncthreads();

  int cur = 0;

  auto step = [&](float eun) {
    const float e  = eun * LOG2E_F;
    const float a2 = abuf[cur][s + 1];          // alpha[s-1]
    float a3       = abuf[cur][s];              // alpha[s-2]
    a3 = skip ? a3 : NEGF;
    const float m   = fmaxf(a1, fmaxf(a2, a3));
    const float sum = FEXP2(a1 - m) + FEXP2(a2 - m) + FEXP2(a3 - m);
    const float an  = m + FLOG2(sum) + e;
    float n256 = 0.0f;
    if (s == 0) {
      // state 256: even (blank) state -> lse2(alpha[256], alpha[255]) + e_blank
      const float b2 = abuf[cur][S];            // state 255
      const float bm = fmaxf(a256, b2);
      const float bs = FEXP2(a256 - bm) + FEXP2(b2 - bm);
      n256 = bm + FLOG2(bs) + e;                // col==0 for s==0 (blank)
    }
    abuf[cur ^ 1][s + 2] = an;
    if (s == 0) abuf[cur ^ 1][S + 1] = n256;
    __syncthreads();
    a1 = an;
    if (s == 0) a256 = n256;
    cur ^= 1;
  };

  const int tmax = plen < T ? plen : T;  // update steps t = 1 .. tmax-1

  // 8-deep prefetch ring (statically indexed -> registers).
  float ef[8];
#pragma unroll
  for (int j = 0; j < 8; ++j) {
    int tt = 1 + j;
    if (tt > T - 1) tt = T - 1;
    ef[j] = prow[tt * C + col];
  }

  int t = 1;
  while (t + 8 <= tmax) {
#pragma unroll
    for (int j = 0; j < 8; ++j) {
      const float e = ef[j];
      int tn = t + j + 8;
      if (tn > T - 1) tn = T - 1;
      ef[j] = prow[tn * C + col];  // refill ring 8 steps ahead
      step(e);
    }
    t += 8;
  }
  while (t < tmax) {
    step(prow[t * C + col]);
    ++t;
  }

  // Readout: loss = -logaddexp(alpha[2tl-1], alpha[2tl]) (natural log), /tl.
  if (s == 0) {
    const float l1 = abuf[cur][2 * tl - 1 + 2];
    const float l2 = abuf[cur][2 * tl + 2];
    const float mm  = fmaxf(l1, l2);
    const float ls2 = mm + FLOG2(FEXP2(l1 - mm) + FEXP2(l2 - mm));
    float per = -(ls2 * LN2_F);
    if (per > 1e29f) per = 0.0f;  // zero_infinity
    const float tlc = (float)(tl > 1 ? tl : 1);
    per_ex[b] = per / tlc;
  }
}

__global__ void ctc_reduce_kernel(const float* __restrict__ per_ex,
                                  float* __restrict__ out, int B)
{
  const int l = threadIdx.x;  // 64 threads, one wave
  float v = 0.0f;
  for (int i = l; i < B; i += 64) v += per_ex[i];
#pragma unroll
  for (int off = 32; off > 0; off >>= 1) v += __shfl_down(v, off);
  if (l == 0) out[0] = v / (float)B;
}

extern "C" void kernel_launch(void* const* d_in, const int* in_sizes, int n_in,
                              void* d_out, int out_size, void* d_ws, size_t ws_size,
                              hipStream_t stream)
{
  const float* pred    = (const float*)d_in[0];
  const int*   targets = (const int*)d_in[1];
  const int*   plen    = (const int*)d_in[2];
  const int*   tlen    = (const int*)d_in[3];
  float*       out     = (float*)d_out;
  float*       ws      = (float*)d_ws;  // B floats of scratch

  constexpr int B = 128, T = 1024, C = 128, L = 128;

  hipLaunchKernelGGL((ctc_alpha_kernel<T, C, L>), dim3(B), dim3(256), 0, stream,
                     pred, targets, plen, tlen, ws);
  hipLaunchKernelGGL(ctc_reduce_kernel, dim3(1), dim3(64), 0, stream,
                     ws, out, B);
}

// Round 2
// 250.195 us; speedup vs baseline: 1.0708x; 1.0708x over previous
//
#include <hip/hip_runtime.h>

// CTC forward loss (log-space alpha recursion), MI355X — single-wave version.
//
// One wave (64 lanes) per batch element. Lane l owns lattice states
// 4l+1 .. 4l+4; state 0 is a degenerate recurrence (a0 += e_blank) tracked
// redundantly in every lane. Even-offset states (4l+2, 4l+4) are blanks ->
// lse2; odd (4l+1, 4l+3) -> lse3. Cross-lane dependency is only the previous
// lane's top two states -> two __shfl_up(x,1) per step. NO barriers, NO LDS
// in the time loop (LDS used once at the end for the readout gather).
// Base-2 log space: v_exp_f32 / v_log_f32 are native base-2.

static constexpr float LOG2E_F = 1.4426950408889634f;
static constexpr float LN2_F   = 0.6931471805599453f;
#define NEGF (-1.0e30f)

#if __has_builtin(__builtin_amdgcn_exp2f)
#define FEXP2(x) __builtin_amdgcn_exp2f(x)
#else
#define FEXP2(x) exp2f(x)
#endif
#if __has_builtin(__builtin_amdgcn_logf)
#define FLOG2(x) __builtin_amdgcn_logf(x)
#else
#define FLOG2(x) __log2f(x)
#endif

template <int T, int C, int L>
__global__ __launch_bounds__(64) void ctc_alpha_wave(
    const float* __restrict__ pred,      // (B,T,C) log-probs
    const int*   __restrict__ targets,   // (B,L)
    const int*   __restrict__ pred_len,  // (B)
    const int*   __restrict__ tgt_len,   // (B)
    float*       __restrict__ per_ex)    // (B) loss / target_len
{
  constexpr int S = 2 * L + 1;  // 257
  const int b = blockIdx.x;
  const int l = threadIdx.x;    // lane 0..63

  __shared__ float afin[S];     // final-alpha gather only (not in the loop)

  const float* __restrict__ prow = pred + (size_t)b * T * C;
  const int plen = pred_len[b];
  const int tl   = tgt_len[b];

  // Emission columns for this lane's odd states (time-invariant).
  const int c1 = targets[b * L + 2 * l];          // state 4l+1
  const int c3 = targets[b * L + 2 * l + 1];      // state 4l+3
  // skip transitions (s-2 -> s), odd states only.
  const bool skip1 = (l == 0) ? false             // state 1: a[-1] is NEG anyway
                              : (c1 != targets[b * L + 2 * l - 1]);
  const bool skip3 = (c3 != c1);

  // t = 0 init (base-2 space): alpha0[0] = e_blank, alpha0[1] = e(tgt0).
  float a0 = prow[0] * LOG2E_F;                   // state 0 (all lanes track)
  float x1 = (l == 0) ? prow[c1] * LOG2E_F : NEGF;
  float x2 = NEGF, x3 = NEGF, x4 = NEGF;

  const int tmax = plen < T ? plen : T;           // steps t = 1 .. tmax-1

  // Prefetch ring, depth 8, statically indexed (registers, not scratch).
  constexpr int D = 8;
  float eb[D], e1[D], e3[D];                      // pre-scaled by log2(e)
#pragma unroll
  for (int j = 0; j < D; ++j) {
    int tt = 1 + j; if (tt > T - 1) tt = T - 1;
    const float* p = prow + (size_t)tt * C;
    eb[j] = p[0]  * LOG2E_F;
    e1[j] = p[c1] * LOG2E_F;
    e3[j] = p[c3] * LOG2E_F;
  }

  auto step = [&](float Eb, float E1, float E3) {
    // prev lane's top two states (state 4l, state 4l-1)
    float P4 = __shfl_up(x4, 1);
    float P3 = __shfl_up(x3, 1);
    if (l == 0) { P4 = a0; P3 = NEGF; }

    // state 4l+1 (odd): lse3(x1, P4, skip1 ? P3)
    const float s1 = skip1 ? P3 : NEGF;
    const float m1 = fmaxf(x1, fmaxf(P4, s1));
    const float n1 = m1 + FLOG2(FEXP2(x1 - m1) + FEXP2(P4 - m1) + FEXP2(s1 - m1)) + E1;
    // state 4l+2 (blank): lse2(x2, x1)
    const float m2 = fmaxf(x2, x1);
    const float n2 = m2 + FLOG2(FEXP2(x2 - m2) + FEXP2(x1 - m2)) + Eb;
    // state 4l+3 (odd): lse3(x3, x2, skip3 ? x1)
    const float s3 = skip3 ? x1 : NEGF;
    const float m3 = fmaxf(x3, fmaxf(x2, s3));
    const float n3 = m3 + FLOG2(FEXP2(x3 - m3) + FEXP2(x2 - m3) + FEXP2(s3 - m3)) + E3;
    // state 4l+4 (blank): lse2(x4, x3)
    const float m4 = fmaxf(x4, x3);
    const float n4 = m4 + FLOG2(FEXP2(x4 - m4) + FEXP2(x3 - m4)) + Eb;
    // state 0: no predecessors
    a0 += Eb;
    x1 = n1; x2 = n2; x3 = n3; x4 = n4;
  };

  int t = 1;
  while (t + D <= tmax) {
#pragma unroll
    for (int j = 0; j < D; ++j) {
      const float Eb = eb[j], E1 = e1[j], E3 = e3[j];
      int tn = t + j + D; if (tn > T - 1) tn = T - 1;
      const float* p = prow + (size_t)tn * C;    // refill 8 steps ahead
      eb[j] = p[0]  * LOG2E_F;
      e1[j] = p[c1] * LOG2E_F;
      e3[j] = p[c3] * LOG2E_F;
      step(Eb, E1, E3);
    }
    t += D;
  }
  // Tail: consume what's left in the ring (static indices, uniform branches).
#pragma unroll
  for (int j = 0; j < D; ++j) {
    if (t + j < tmax) step(eb[j], e1[j], e3[j]);
  }

  // Readout: per_ex = -logaddexp(alpha[2tl-1], alpha[2tl]) / tl  (natural log)
  afin[4 * l + 1] = x1;
  afin[4 * l + 2] = x2;
  afin[4 * l + 3] = x3;
  afin[4 * l + 4] = x4;
  if (l == 0) afin[0] = a0;
  __syncthreads();
  if (l == 0) {
    const float l1 = afin[2 * tl - 1];
    const float l2 = afin[2 * tl];
    const float mm = fmaxf(l1, l2);
    const float ls = mm + FLOG2(FEXP2(l1 - mm) + FEXP2(l2 - mm));
    float per = -(ls * LN2_F);
    if (per > 1e29f) per = 0.0f;                 // zero_infinity
    per_ex[b] = per / (float)(tl > 1 ? tl : 1);
  }
}

__global__ void ctc_reduce_kernel(const float* __restrict__ per_ex,
                                  float* __restrict__ out, int B)
{
  const int l = threadIdx.x;  // one wave
  float v = 0.0f;
  for (int i = l; i < B; i += 64) v += per_ex[i];
#pragma unroll
  for (int off = 32; off > 0; off >>= 1) v += __shfl_down(v, off);
  if (l == 0) out[0] = v / (float)B;
}

extern "C" void kernel_launch(void* const* d_in, const int* in_sizes, int n_in,
                              void* d_out, int out_size, void* d_ws, size_t ws_size,
                              hipStream_t stream)
{
  const float* pred    = (const float*)d_in[0];
  const int*   targets = (const int*)d_in[1];
  const int*   plen    = (const int*)d_in[2];
  const int*   tlen    = (const int*)d_in[3];
  float*       out     = (float*)d_out;
  float*       ws      = (float*)d_ws;  // B floats scratch

  constexpr int B = 128, T = 1024, C = 128, L = 128;

  hipLaunchKernelGGL((ctc_alpha_wave<T, C, L>), dim3(B), dim3(64), 0, stream,
                     pred, targets, plen, tlen, ws);
  hipLaunchKernelGGL(ctc_reduce_kernel, dim3(1), dim3(64), 0, stream,
                     ws, out, B);
}